// Round 17
// baseline (140.671 us; speedup 1.0000x reference)
//
#include <hip/hip_runtime.h>
#include <hip/hip_bf16.h>

typedef short s16x8 __attribute__((ext_vector_type(8)));
typedef short s16x4 __attribute__((ext_vector_type(4)));
typedef float f32x4 __attribute__((ext_vector_type(4)));
typedef float f32x16 __attribute__((ext_vector_type(16)));
typedef unsigned int u32x4 __attribute__((ext_vector_type(4)));

#define S_LEN 2048
#define DMODEL 1024
#define NHEAD 16
#define HDIM 64
#define OUT_ELEMS 4194304   // B*S*D
#define HEAD_ELEMS 4194304  // B*H*S*HD
#define SCALE_LOG2 0.1803368801111204f  // 0.125 * log2(e), folded into Q

__device__ inline short f2bf(float f) {
  __hip_bfloat16 h = __float2bfloat16(f);  // RNE
  return __builtin_bit_cast(short, h);
}

__device__ inline f32x4 mfma16(s16x8 a, s16x8 b, f32x4 c) {
  return __builtin_amdgcn_mfma_f32_16x16x32_bf16(a, b, c, 0, 0, 0);
}
__device__ inline f32x16 mfma32(s16x8 a, s16x8 b, f32x16 c) {
  return __builtin_amdgcn_mfma_f32_32x32x16_bf16(a, b, c, 0, 0, 0);
}

typedef __attribute__((address_space(1))) const void gvoid;
typedef __attribute__((address_space(3))) void lvoid;
__device__ inline void gload_lds16(const void* g, void* l) {
  __builtin_amdgcn_global_load_lds((gvoid*)g, (lvoid*)l, 16, 0, 0);
}

// ---- fused preprocessing: x f32->bf16 ++ wqkv transpose ++ wproj transpose
__global__ __launch_bounds__(256) void preproc(
    const float* __restrict__ x, short* __restrict__ xbf,
    const float* __restrict__ w_qkv, short* __restrict__ wqkvT,
    const float* __restrict__ w_proj, short* __restrict__ wprojT) {
  const int p = blockIdx.x;
  const int t = threadIdx.x;
  if (p < 2048) {
    int g = p * 256 + t;
    const float* sp = &x[(size_t)g * 8];
    f32x4 a = *(const f32x4*)sp;
    f32x4 b = *(const f32x4*)(sp + 4);
    s16x8 v;
#pragma unroll
    for (int j = 0; j < 4; j++) {
      v[j] = f2bf(a[j]);
      v[4 + j] = f2bf(b[j]);
    }
    *(s16x8*)&xbf[(size_t)g * 8] = v;
  } else if (p < 3584) {
    int g = (p - 2048) * 256 + t;
    int c = g % 3072;
    int r0 = (g / 3072) * 8;
    s16x8 v;
#pragma unroll
    for (int j = 0; j < 8; j++) v[j] = f2bf(w_qkv[(size_t)(r0 + j) * 3072 + c]);
    *(s16x8*)&wqkvT[(size_t)c * 1024 + r0] = v;
  } else {
    int g = (p - 3584) * 256 + t;
    int c = g % 1024;
    int r0 = (g / 1024) * 8;
    s16x8 v;
#pragma unroll
    for (int j = 0; j < 8; j++) v[j] = f2bf(w_proj[(size_t)(r0 + j) * 1024 + c]);
    *(s16x8*)&wprojT[(size_t)c * 1024 + r0] = v;
  }
}

// ---- fused K/V fragment repack: [0,koff) kfrag, [koff,..) vfrag ----------
__global__ __launch_bounds__(256) void kvfrag(const float* __restrict__ Kp,
                                              const float* __restrict__ Vp,
                                              short* __restrict__ Kf,
                                              short* __restrict__ Vf,
                                              int koff) {
  __shared__ short Ls[128][66];
  const int t = threadIdx.x;
  if ((int)blockIdx.x < koff) {
    const int p = blockIdx.x;
    const int bh = p & 31;
    const int blk4 = p >> 5;
    const float* src = Kp + ((size_t)bh * S_LEN + (size_t)blk4 * 128) * HDIM;
#pragma unroll
    for (int rep = 0; rep < 8; rep++) {
      int idx = rep * 256 + t;
      int row = idx >> 4, ch = idx & 15;
      f32x4 a = *(const f32x4*)&src[row * 64 + ch * 4];
      s16x4 v;
#pragma unroll
      for (int j = 0; j < 4; j++) v[j] = f2bf(a[j]);
      *(s16x4*)&Ls[row][ch * 4] = v;
    }
    __syncthreads();
    const int c = t >> 6, lane = t & 63;
    const int l32 = lane & 31, hi = lane >> 5;
    short* dst = Kf + (((size_t)bh * 64 + blk4 * 4) * 4 + c) * 512 + lane * 8;
#pragma unroll
    for (int q = 0; q < 4; q++) {
      s16x8 v = *(const s16x8*)&Ls[q * 32 + l32][c * 16 + hi * 8];
      *(s16x8*)&dst[(size_t)q * 4 * 512] = v;
    }
  } else {
    const int p = blockIdx.x - koff;
    const int bh = p & 31;
    const int kt64 = p >> 5;
    const float* src = Vp + ((size_t)bh * S_LEN + (size_t)kt64 * 64) * HDIM;
#pragma unroll
    for (int rep = 0; rep < 4; rep++) {
      int idx = rep * 256 + t;
      int row = idx >> 4, ch = idx & 15;
      f32x4 a = *(const f32x4*)&src[row * 64 + ch * 4];
      s16x4 v;
#pragma unroll
      for (int j = 0; j < 4; j++) v[j] = f2bf(a[j]);
      *(s16x4*)&Ls[row][ch * 4] = v;
    }
    __syncthreads();
    const int stkc = t >> 6, lane = t & 63;
    const int st = stkc >> 1, kc = stkc & 1;
    const int l32 = lane & 31, hi = lane >> 5;
    const int rowbase = st * 32 + kc * 16 + (hi ? 4 : 0);
#pragma unroll
    for (int f = 0; f < 2; f++) {
      int col = f * 32 + l32;
      s16x8 v;
#pragma unroll
      for (int u = 0; u < 4; u++) {
        v[u] = Ls[rowbase + u][col];
        v[4 + u] = Ls[rowbase + 8 + u][col];
      }
      size_t o = (((size_t)bh * 64 + kt64 * 2 + st) * 4 + kc * 2 + f) * 512 +
                 lane * 8;
      *(s16x8*)&Vf[o] = v;
    }
  }
}

// ---- GEMM (round-14 proven): bf16, gload_lds, BK=64, swizzle, 1 buffer ----
// MODE 0: QKV scatter. MODE 1: plain f32 row-major.
template <int MODE>
__global__ __launch_bounds__(256) void gemm_bt(
    const short* __restrict__ A, const short* __restrict__ Bt,
    const float* __restrict__ bias, short* __restrict__ Ob0,
    float* __restrict__ Of, int M, int N, int K) {
  __shared__ short As[128 * 64];
  __shared__ short Bs[128 * 64];
  const int t = threadIdx.x;
  const int lane = t & 63;
  const int wid = t >> 6;
  const int wr = wid >> 1, wc = wid & 1;
  const int l16 = lane & 15, lg = lane >> 4;
  const int mbase = blockIdx.y * 128;
  const int nbase = blockIdx.x * 128;

  f32x4 acc[4][4];
#pragma unroll
  for (int m = 0; m < 4; m++)
#pragma unroll
    for (int n = 0; n < 4; n++) acc[m][n] = (f32x4){0.f, 0.f, 0.f, 0.f};

  const int srow = lane >> 3;
  const int sgr = (lane & 7) ^ srow;
  const short* Ag = &A[(size_t)(mbase + wid * 32 + srow) * K + sgr * 8];
  const short* Bg = &Bt[(size_t)(nbase + wid * 32 + srow) * K + sgr * 8];

  for (int k0 = 0; k0 < K; k0 += 64) {
    __syncthreads();
#pragma unroll
    for (int c = 0; c < 4; c++)
      gload_lds16(Ag + (size_t)(c * 8) * K + k0, &As[(wid * 32 + c * 8) * 64]);
#pragma unroll
    for (int c = 0; c < 4; c++)
      gload_lds16(Bg + (size_t)(c * 8) * K + k0, &Bs[(wid * 32 + c * 8) * 64]);
    __syncthreads();
    s16x8 af[4][2], bfr[4][2];
#pragma unroll
    for (int m = 0; m < 4; m++) {
      int row = wr * 64 + m * 16 + l16;
#pragma unroll
      for (int h = 0; h < 2; h++) {
        int gr = (h * 4 + lg) ^ (row & 7);
        af[m][h] = *(const s16x8*)&As[row * 64 + gr * 8];
      }
    }
#pragma unroll
    for (int n = 0; n < 4; n++) {
      int row = wc * 64 + n * 16 + l16;
#pragma unroll
      for (int h = 0; h < 2; h++) {
        int gr = (h * 4 + lg) ^ (row & 7);
        bfr[n][h] = *(const s16x8*)&Bs[row * 64 + gr * 8];
      }
    }
#pragma unroll
    for (int m = 0; m < 4; m++)
#pragma unroll
      for (int n = 0; n < 4; n++) {
        acc[m][n] = mfma16(af[m][0], bfr[n][0], acc[m][n]);
        acc[m][n] = mfma16(af[m][1], bfr[n][1], acc[m][n]);
      }
  }

#pragma unroll
  for (int m = 0; m < 4; m++) {
#pragma unroll
    for (int n = 0; n < 4; n++) {
      int gcol = nbase + wc * 64 + n * 16 + l16;
      float bv = bias[gcol];
      int part = gcol >> 10;
      int cin = gcol & 1023;
      int h = cin >> 6, hd = cin & 63;
      int grow0 = mbase + wr * 64 + m * 16 + lg * 4;
      float vr[4];
#pragma unroll
      for (int r = 0; r < 4; r++) vr[r] = acc[m][n][r] + bv;
      if (MODE == 0) {
        int bb = grow0 >> 11, s0 = grow0 & 2047;
        size_t base = ((size_t)(bb * NHEAD + h) * S_LEN + s0) * HDIM + hd;
        if (part == 0) {
#pragma unroll
          for (int r = 0; r < 4; r++)
            Ob0[base + (size_t)r * HDIM] = f2bf(vr[r] * SCALE_LOG2);
        } else if (part == 1) {
#pragma unroll
          for (int r = 0; r < 4; r++) Of[base + (size_t)r * HDIM] = vr[r];
        } else {
#pragma unroll
          for (int r = 0; r < 4; r++)
            Of[HEAD_ELEMS + base + (size_t)r * HDIM] = vr[r];
        }
      } else {
#pragma unroll
        for (int r = 0; r < 4; r++) Of[(size_t)(grow0 + r) * N + gcol] = vr[r];
      }
    }
  }
}

// ==== attention: round-12 structure + K AND V register prefetch (T14) ====
template <bool KFRAG>
__device__ __forceinline__ void attn_body(const short* __restrict__ Q,
                                          const void* __restrict__ Kraw,
                                          const short* __restrict__ Vf,
                                          short* __restrict__ AO) {
  __shared__ float XFER[2][64][37];

  const int p = blockIdx.x;
  const int xcd = p & 7;
  const int rank = p >> 3;
  const int bh = (xcd << 2) | (rank >> 5);
  const int pr = rank & 31;

  const int tid = threadIdx.x;
  const int w = tid >> 6;
  const int lane = tid & 63;
  const int l32 = lane & 31;
  const int hi = lane >> 5;

  const short* Qb = Q + (size_t)bh * (S_LEN * HDIM);
  const short* Kfb = (const short*)Kraw + (size_t)bh * (64 * 2048);
  const float* Kb32 = (const float*)Kraw + (size_t)bh * (S_LEN * HDIM);
  const short* Vfb = Vf + (size_t)bh * (64 * 2048);
  const int b = bh >> 4, h = bh & 15;

#pragma unroll 1
  for (int ph = 0; ph < 2; ph++) {
    const int j = ph ? pr : 63 - pr;
    const int qb = j * 32;

    s16x8 qf[4];
#pragma unroll
    for (int c = 0; c < 4; c++)
      qf[c] = *(const s16x8*)&Qb[(size_t)(qb + l32) * HDIM + c * 16 + hi * 8];

    f32x16 acc0 = {0.f}, acc1 = {0.f};
    float m = -1e30f, ll = 0.f;

    s16x8 kcur[4], vcur[4];
    if constexpr (KFRAG) {
      if (w <= j) {
#pragma unroll
        for (int c = 0; c < 4; c++)
          kcur[c] =
              *(const s16x8*)&Kfb[(size_t)w * 2048 + c * 512 + lane * 8];
#pragma unroll
        for (int c = 0; c < 4; c++)
          vcur[c] =
              *(const s16x8*)&Vfb[(size_t)w * 2048 + c * 512 + lane * 8];
      }
    }

#pragma unroll 1
    for (int kt = w; kt <= j; kt += 4) {
      f32x16 S = {0.f};
      s16x8 va00, va10, va01, va11;
      if constexpr (KFRAG) {
#pragma unroll
        for (int c = 0; c < 4; c++) S = mfma32(kcur[c], qf[c], S);
        va00 = vcur[0];
        va10 = vcur[1];
        va01 = vcur[2];
        va11 = vcur[3];
        // prefetch next tile's K AND V a full trip ahead (T14)
        if (kt + 4 <= j) {
#pragma unroll
          for (int c = 0; c < 4; c++)
            kcur[c] = *(const s16x8*)&Kfb[(size_t)(kt + 4) * 2048 + c * 512 +
                                          lane * 8];
#pragma unroll
          for (int c = 0; c < 4; c++)
            vcur[c] = *(const s16x8*)&Vfb[(size_t)(kt + 4) * 2048 + c * 512 +
                                          lane * 8];
        }
      } else {
        const int kb = kt * 32;
#pragma unroll
        for (int c = 0; c < 4; c++) {
          const float* kr = &Kb32[(size_t)(kb + l32) * HDIM + c * 16 + hi * 8];
          f32x4 k0 = *(const f32x4*)kr, k1 = *(const f32x4*)(kr + 4);
          s16x8 kf;
#pragma unroll
          for (int u = 0; u < 4; u++) {
            kf[u] = f2bf(k0[u]);
            kf[4 + u] = f2bf(k1[u]);
          }
          S = mfma32(kf, qf[c], S);
        }
        const short* vb = &Vfb[(size_t)kt * 2048 + lane * 8];
        va00 = *(const s16x8*)vb;
        va10 = *(const s16x8*)(vb + 512);
        va01 = *(const s16x8*)(vb + 1024);
        va11 = *(const s16x8*)(vb + 1536);
      }
      if (kt == j) {
#pragma unroll
        for (int r = 0; r < 16; r++) {
          int keyl = (r & 3) + 8 * (r >> 2) + 4 * hi;
          S[r] = (keyl <= l32) ? S[r] : -1e30f;
        }
      }
      float t8[8];
#pragma unroll
      for (int r = 0; r < 8; r++) t8[r] = fmaxf(S[2 * r], S[2 * r + 1]);
      float tmax = fmaxf(fmaxf(fmaxf(t8[0], t8[1]), fmaxf(t8[2], t8[3])),
                         fmaxf(fmaxf(t8[4], t8[5]), fmaxf(t8[6], t8[7])));
      tmax = fmaxf(tmax, __shfl_xor(tmax, 32));
      if (!__all(tmax <= m + 11.0f)) {
        float mn = fmaxf(m, tmax);
        float alpha = __builtin_amdgcn_exp2f(m - mn);
        ll *= alpha;
#pragma unroll
        for (int r = 0; r < 16; r++) {
          acc0[r] *= alpha;
          acc1[r] *= alpha;
        }
        m = mn;
      }
#pragma unroll
      for (int r = 0; r < 16; r++) S[r] = __builtin_amdgcn_exp2f(S[r] - m);
      float s8[8];
#pragma unroll
      for (int r = 0; r < 8; r++) s8[r] = S[2 * r] + S[2 * r + 1];
      float rs = ((s8[0] + s8[1]) + (s8[2] + s8[3])) +
                 ((s8[4] + s8[5]) + (s8[6] + s8[7]));
      rs += __shfl_xor(rs, 32);
      ll += rs;
      u32x4 pb0v, pb1v;
#pragma unroll
      for (int g = 0; g < 4; g++) {
        unsigned int lo = (unsigned short)f2bf(S[2 * g]);
        unsigned int h16 = (unsigned short)f2bf(S[2 * g + 1]);
        pb0v[g] = lo | (h16 << 16);
        unsigned int lo2 = (unsigned short)f2bf(S[8 + 2 * g]);
        unsigned int h162 = (unsigned short)f2bf(S[9 + 2 * g]);
        pb1v[g] = lo2 | (h162 << 16);
      }
      s16x8 pb0 = __builtin_bit_cast(s16x8, pb0v);
      s16x8 pb1 = __builtin_bit_cast(s16x8, pb1v);
      acc0 = mfma32(va00, pb0, acc0);
      acc1 = mfma32(va10, pb0, acc1);
      acc0 = mfma32(va01, pb1, acc0);
      acc1 = mfma32(va11, pb1, acc1);
    }

    // ---- combine the 4 per-wave partials (tree merge via LDS) ----
    if (w & 1) {
      float* dst = &XFER[w >> 1][lane][0];
      dst[0] = m; dst[1] = ll;
#pragma unroll
      for (int r = 0; r < 16; r++) { dst[2 + r] = acc0[r]; dst[18 + r] = acc1[r]; }
    }
    __syncthreads();
    if (!(w & 1)) {
      const float* src = &XFER[w >> 1][lane][0];
      float m2 = src[0], l2 = src[1];
      float M = fmaxf(m, m2);
      float a1 = __builtin_amdgcn_exp2f(m - M);
      float a2 = __builtin_amdgcn_exp2f(m2 - M);
      ll = ll * a1 + l2 * a2;
#pragma unroll
      for (int r = 0; r < 16; r++) {
        acc0[r] = acc0[r] * a1 + src[2 + r] * a2;
        acc1[r] = acc1[r] * a1 + src[18 + r] * a2;
      }
      m = M;
    }
    __syncthreads();
    if (w == 2) {
      float* dst = &XFER[0][lane][0];
      dst[0] = m; dst[1] = ll;
#pragma unroll
      for (int r = 0; r < 16; r++) { dst[2 + r] = acc0[r]; dst[18 + r] = acc1[r]; }
    }
    __syncthreads();
    if (w == 0) {
      const float* src = &XFER[0][lane][0];
      float m2 = src[0], l2 = src[1];
      float M = fmaxf(m, m2);
      float a1 = __builtin_amdgcn_exp2f(m - M);
      float a2 = __builtin_amdgcn_exp2f(m2 - M);
      ll = ll * a1 + l2 * a2;
#pragma unroll
      for (int r = 0; r < 16; r++) {
        acc0[r] = acc0[r] * a1 + src[2 + r] * a2;
        acc1[r] = acc1[r] * a1 + src[18 + r] * a2;
      }
      float inv = 1.f / ll;
      size_t rowbase = ((size_t)(b * S_LEN + qb + l32)) * DMODEL + h * HDIM;
#pragma unroll
      for (int g = 0; g < 4; g++) {
        s16x4 o0, o1;
#pragma unroll
        for (int u = 0; u < 4; u++) {
          o0[u] = f2bf(acc0[4 * g + u] * inv);
          o1[u] = f2bf(acc1[4 * g + u] * inv);
        }
        *(s16x4*)&AO[rowbase + 8 * g + 4 * hi] = o0;
        *(s16x4*)&AO[rowbase + 32 + 8 * g + 4 * hi] = o1;
      }
    }
    __syncthreads();
  }
}

__global__ __launch_bounds__(256, 4) void attn_fwd_frag(
    const short* __restrict__ Q, const short* __restrict__ Kf,
    const short* __restrict__ Vf, short* __restrict__ AO) {
  attn_body<true>(Q, Kf, Vf, AO);
}
__global__ __launch_bounds__(256, 4) void attn_fwd_kf32(
    const short* __restrict__ Q, const float* __restrict__ K,
    const short* __restrict__ Vf, short* __restrict__ AO) {
  attn_body<false>(Q, K, Vf, AO);
}

extern "C" void kernel_launch(void* const* d_in, const int* in_sizes, int n_in,
                              void* d_out, int out_size, void* d_ws,
                              size_t ws_size, hipStream_t stream) {
  const float* x = (const float*)d_in[0];
  const float* w_qkv = (const float*)d_in[1];
  const float* b_qkv = (const float*)d_in[2];
  const float* w_proj = (const float*)d_in[3];
  const float* b_proj = (const float*)d_in[4];
  float* out = (float*)d_out;
  float* presentK = out + OUT_ELEMS;            // f32 [bh][S][64]
  float* presentV = presentK + HEAD_ELEMS;      // f32 [bh][S][64]

  short* xbf = (short*)out;  // dead-until-proj region

  short* ws = (short*)d_ws;
  const bool kbf16 = ws_size >= (size_t)35651584;

  short *Qw, *Vf, *wprojT, *wqkvT, *attnout, *Kf;
  if (kbf16) {
    Qw = ws;
    Kf = ws + 4194304;
    Vf = ws + 8388608;
    wprojT = ws + 12582912;
    wqkvT = ws + 13631488;
    attnout = ws + 13631488;
  } else {
    if (ws_size < (size_t)27262976) return;
    Qw = ws;
    Vf = ws + 4194304;
    wprojT = ws + 8388608;
    wqkvT = ws + 9437184;
    attnout = ws + 9437184;
    Kf = nullptr;
  }

  // fused preprocessing (x cvt + both weight transposes)
  preproc<<<dim3(4096), 256, 0, stream>>>(x, xbf, w_qkv, wqkvT, w_proj,
                                          wprojT);
  // QKV projection: Q(pre-scaled)->Qw bf16, K/V->present f32
  gemm_bt<0><<<dim3(24, 32), 256, 0, stream>>>(xbf, wqkvT, b_qkv, Qw,
                                               presentK, 4096, 3072, 1024);
  // fused fragment-linear repacks
  {
    int koff = kbf16 ? 512 : 0;
    kvfrag<<<dim3(koff + 1024), 256, 0, stream>>>(presentK, presentV, Kf, Vf,
                                                  koff);
  }
  // causal attention
  if (kbf16)
    attn_fwd_frag<<<dim3(1024), 256, 0, stream>>>(Qw, Kf, Vf, attnout);
  else
    attn_fwd_kf32<<<dim3(1024), 256, 0, stream>>>(Qw, presentK, Vf, attnout);
  // output projection -> f32 out (xbf dead by now)
  gemm_bt<1><<<dim3(8, 32), 256, 0, stream>>>(attnout, wprojT, b_proj,
                                              nullptr, out, 4096, 1024, 1024);
}

// Round 18
// 112.601 us; speedup vs baseline: 1.2493x; 1.2493x over previous
//
#include <hip/hip_runtime.h>
#include <hip/hip_bf16.h>

typedef short s16x8 __attribute__((ext_vector_type(8)));
typedef short s16x4 __attribute__((ext_vector_type(4)));
typedef float f32x4 __attribute__((ext_vector_type(4)));
typedef float f32x16 __attribute__((ext_vector_type(16)));
typedef unsigned int u32x4 __attribute__((ext_vector_type(4)));

#define S_LEN 2048
#define DMODEL 1024
#define NHEAD 16
#define HDIM 64
#define OUT_ELEMS 4194304   // B*S*D
#define HEAD_ELEMS 4194304  // B*H*S*HD
#define SCALE_LOG2 0.1803368801111204f  // 0.125 * log2(e), folded into Q

__device__ inline short f2bf(float f) {
  __hip_bfloat16 h = __float2bfloat16(f);  // RNE
  return __builtin_bit_cast(short, h);
}

__device__ inline f32x4 mfma16(s16x8 a, s16x8 b, f32x4 c) {
  return __builtin_amdgcn_mfma_f32_16x16x32_bf16(a, b, c, 0, 0, 0);
}
__device__ inline f32x16 mfma32(s16x8 a, s16x8 b, f32x16 c) {
  return __builtin_amdgcn_mfma_f32_32x32x16_bf16(a, b, c, 0, 0, 0);
}

typedef __attribute__((address_space(1))) const void gvoid;
typedef __attribute__((address_space(3))) void lvoid;
__device__ inline void gload_lds16(const void* g, void* l) {
  __builtin_amdgcn_global_load_lds((gvoid*)g, (lvoid*)l, 16, 0, 0);
}

// ---- fused preprocessing: x f32->bf16 ++ wqkv transpose ++ wproj transpose
// grid 4096: [0,2048) cvt, [2048,3584) wqkv T, [3584,4096) wproj T
__global__ __launch_bounds__(256) void preproc(
    const float* __restrict__ x, short* __restrict__ xbf,
    const float* __restrict__ w_qkv, short* __restrict__ wqkvT,
    const float* __restrict__ w_proj, short* __restrict__ wprojT) {
  const int p = blockIdx.x;
  const int t = threadIdx.x;
  if (p < 2048) {
    int g = p * 256 + t;
    const float* sp = &x[(size_t)g * 8];
    f32x4 a = *(const f32x4*)sp;
    f32x4 b = *(const f32x4*)(sp + 4);
    s16x8 v;
#pragma unroll
    for (int j = 0; j < 4; j++) {
      v[j] = f2bf(a[j]);
      v[4 + j] = f2bf(b[j]);
    }
    *(s16x8*)&xbf[(size_t)g * 8] = v;
  } else if (p < 3584) {
    int g = (p - 2048) * 256 + t;
    int c = g % 3072;
    int r0 = (g / 3072) * 8;
    s16x8 v;
#pragma unroll
    for (int j = 0; j < 8; j++) v[j] = f2bf(w_qkv[(size_t)(r0 + j) * 3072 + c]);
    *(s16x8*)&wqkvT[(size_t)c * 1024 + r0] = v;
  } else {
    int g = (p - 3584) * 256 + t;
    int c = g % 1024;
    int r0 = (g / 1024) * 8;
    s16x8 v;
#pragma unroll
    for (int j = 0; j < 8; j++) v[j] = f2bf(w_proj[(size_t)(r0 + j) * 1024 + c]);
    *(s16x8*)&wprojT[(size_t)c * 1024 + r0] = v;
  }
}

// ---- fused K/V fragment repack: [0,koff) kfrag, [koff,..) vfrag ----------
__global__ __launch_bounds__(256) void kvfrag(const float* __restrict__ Kp,
                                              const float* __restrict__ Vp,
                                              short* __restrict__ Kf,
                                              short* __restrict__ Vf,
                                              int koff) {
  __shared__ short Ls[128][66];
  const int t = threadIdx.x;
  if ((int)blockIdx.x < koff) {
    const int p = blockIdx.x;
    const int bh = p & 31;
    const int blk4 = p >> 5;
    const float* src = Kp + ((size_t)bh * S_LEN + (size_t)blk4 * 128) * HDIM;
#pragma unroll
    for (int rep = 0; rep < 8; rep++) {
      int idx = rep * 256 + t;
      int row = idx >> 4, ch = idx & 15;
      f32x4 a = *(const f32x4*)&src[row * 64 + ch * 4];
      s16x4 v;
#pragma unroll
      for (int j = 0; j < 4; j++) v[j] = f2bf(a[j]);
      *(s16x4*)&Ls[row][ch * 4] = v;
    }
    __syncthreads();
    const int c = t >> 6, lane = t & 63;
    const int l32 = lane & 31, hi = lane >> 5;
    short* dst = Kf + (((size_t)bh * 64 + blk4 * 4) * 4 + c) * 512 + lane * 8;
#pragma unroll
    for (int q = 0; q < 4; q++) {
      s16x8 v = *(const s16x8*)&Ls[q * 32 + l32][c * 16 + hi * 8];
      *(s16x8*)&dst[(size_t)q * 4 * 512] = v;
    }
  } else {
    const int p = blockIdx.x - koff;
    const int bh = p & 31;
    const int kt64 = p >> 5;
    const float* src = Vp + ((size_t)bh * S_LEN + (size_t)kt64 * 64) * HDIM;
#pragma unroll
    for (int rep = 0; rep < 4; rep++) {
      int idx = rep * 256 + t;
      int row = idx >> 4, ch = idx & 15;
      f32x4 a = *(const f32x4*)&src[row * 64 + ch * 4];
      s16x4 v;
#pragma unroll
      for (int j = 0; j < 4; j++) v[j] = f2bf(a[j]);
      *(s16x4*)&Ls[row][ch * 4] = v;
    }
    __syncthreads();
    const int stkc = t >> 6, lane = t & 63;
    const int st = stkc >> 1, kc = stkc & 1;
    const int l32 = lane & 31, hi = lane >> 5;
    const int rowbase = st * 32 + kc * 16 + (hi ? 4 : 0);
#pragma unroll
    for (int f = 0; f < 2; f++) {
      int col = f * 32 + l32;
      s16x8 v;
#pragma unroll
      for (int u = 0; u < 4; u++) {
        v[u] = Ls[rowbase + u][col];
        v[4 + u] = Ls[rowbase + 8 + u][col];
      }
      size_t o = (((size_t)bh * 64 + kt64 * 2 + st) * 4 + kc * 2 + f) * 512 +
                 lane * 8;
      *(s16x8*)&Vf[o] = v;
    }
  }
}

// ---- GEMM (round-14 proven): bf16, gload_lds, BK=64, swizzle, 1 buffer ----
// MODE 0: QKV scatter. MODE 1: plain f32 row-major.
template <int MODE>
__global__ __launch_bounds__(256) void gemm_bt(
    const short* __restrict__ A, const short* __restrict__ Bt,
    const float* __restrict__ bias, short* __restrict__ Ob0,
    float* __restrict__ Of, int M, int N, int K) {
  __shared__ short As[128 * 64];
  __shared__ short Bs[128 * 64];
  const int t = threadIdx.x;
  const int lane = t & 63;
  const int wid = t >> 6;
  const int wr = wid >> 1, wc = wid & 1;
  const int l16 = lane & 15, lg = lane >> 4;
  const int mbase = blockIdx.y * 128;
  const int nbase = blockIdx.x * 128;

  f32x4 acc[4][4];
#pragma unroll
  for (int m = 0; m < 4; m++)
#pragma unroll
    for (int n = 0; n < 4; n++) acc[m][n] = (f32x4){0.f, 0.f, 0.f, 0.f};

  const int srow = lane >> 3;
  const int sgr = (lane & 7) ^ srow;
  const short* Ag = &A[(size_t)(mbase + wid * 32 + srow) * K + sgr * 8];
  const short* Bg = &Bt[(size_t)(nbase + wid * 32 + srow) * K + sgr * 8];

  for (int k0 = 0; k0 < K; k0 += 64) {
    __syncthreads();
#pragma unroll
    for (int c = 0; c < 4; c++)
      gload_lds16(Ag + (size_t)(c * 8) * K + k0, &As[(wid * 32 + c * 8) * 64]);
#pragma unroll
    for (int c = 0; c < 4; c++)
      gload_lds16(Bg + (size_t)(c * 8) * K + k0, &Bs[(wid * 32 + c * 8) * 64]);
    __syncthreads();
    s16x8 af[4][2], bfr[4][2];
#pragma unroll
    for (int m = 0; m < 4; m++) {
      int row = wr * 64 + m * 16 + l16;
#pragma unroll
      for (int h = 0; h < 2; h++) {
        int gr = (h * 4 + lg) ^ (row & 7);
        af[m][h] = *(const s16x8*)&As[row * 64 + gr * 8];
      }
    }
#pragma unroll
    for (int n = 0; n < 4; n++) {
      int row = wc * 64 + n * 16 + l16;
#pragma unroll
      for (int h = 0; h < 2; h++) {
        int gr = (h * 4 + lg) ^ (row & 7);
        bfr[n][h] = *(const s16x8*)&Bs[row * 64 + gr * 8];
      }
    }
#pragma unroll
    for (int m = 0; m < 4; m++)
#pragma unroll
      for (int n = 0; n < 4; n++) {
        acc[m][n] = mfma16(af[m][0], bfr[n][0], acc[m][n]);
        acc[m][n] = mfma16(af[m][1], bfr[n][1], acc[m][n]);
      }
  }

#pragma unroll
  for (int m = 0; m < 4; m++) {
#pragma unroll
    for (int n = 0; n < 4; n++) {
      int gcol = nbase + wc * 64 + n * 16 + l16;
      float bv = bias[gcol];
      int part = gcol >> 10;
      int cin = gcol & 1023;
      int h = cin >> 6, hd = cin & 63;
      int grow0 = mbase + wr * 64 + m * 16 + lg * 4;
      float vr[4];
#pragma unroll
      for (int r = 0; r < 4; r++) vr[r] = acc[m][n][r] + bv;
      if (MODE == 0) {
        int bb = grow0 >> 11, s0 = grow0 & 2047;
        size_t base = ((size_t)(bb * NHEAD + h) * S_LEN + s0) * HDIM + hd;
        if (part == 0) {
#pragma unroll
          for (int r = 0; r < 4; r++)
            Ob0[base + (size_t)r * HDIM] = f2bf(vr[r] * SCALE_LOG2);
        } else if (part == 1) {
#pragma unroll
          for (int r = 0; r < 4; r++) Of[base + (size_t)r * HDIM] = vr[r];
        } else {
#pragma unroll
          for (int r = 0; r < 4; r++)
            Of[HEAD_ELEMS + base + (size_t)r * HDIM] = vr[r];
        }
      } else {
#pragma unroll
        for (int r = 0; r < 4; r++) Of[(size_t)(grow0 + r) * N + gcol] = vr[r];
      }
    }
  }
}

// ==== attention: round-12/14 proven structure (fragment-linear K/V, ========
// ==== k-split across 4 waves + LDS combine, K register prefetch) ==========
template <bool KFRAG>
__device__ __forceinline__ void attn_body(const short* __restrict__ Q,
                                          const void* __restrict__ Kraw,
                                          const short* __restrict__ Vf,
                                          short* __restrict__ AO) {
  __shared__ float XFER[2][64][37];

  const int p = blockIdx.x;
  const int xcd = p & 7;
  const int rank = p >> 3;
  const int bh = (xcd << 2) | (rank >> 5);
  const int pr = rank & 31;

  const int tid = threadIdx.x;
  const int w = tid >> 6;
  const int lane = tid & 63;
  const int l32 = lane & 31;
  const int hi = lane >> 5;

  const short* Qb = Q + (size_t)bh * (S_LEN * HDIM);
  const short* Kfb = (const short*)Kraw + (size_t)bh * (64 * 2048);
  const float* Kb32 = (const float*)Kraw + (size_t)bh * (S_LEN * HDIM);
  const short* Vfb = Vf + (size_t)bh * (64 * 2048);
  const int b = bh >> 4, h = bh & 15;

#pragma unroll 1
  for (int ph = 0; ph < 2; ph++) {
    const int j = ph ? pr : 63 - pr;
    const int qb = j * 32;

    s16x8 qf[4];
#pragma unroll
    for (int c = 0; c < 4; c++)
      qf[c] = *(const s16x8*)&Qb[(size_t)(qb + l32) * HDIM + c * 16 + hi * 8];

    f32x16 acc0 = {0.f}, acc1 = {0.f};
    float m = -1e30f, ll = 0.f;

    s16x8 kcur[4];
    if constexpr (KFRAG) {
      if (w <= j) {
#pragma unroll
        for (int c = 0; c < 4; c++)
          kcur[c] =
              *(const s16x8*)&Kfb[(size_t)w * 2048 + c * 512 + lane * 8];
      }
    }

#pragma unroll 1
    for (int kt = w; kt <= j; kt += 4) {
      f32x16 S = {0.f};
      if constexpr (KFRAG) {
#pragma unroll
        for (int c = 0; c < 4; c++) S = mfma32(kcur[c], qf[c], S);
      } else {
        const int kb = kt * 32;
#pragma unroll
        for (int c = 0; c < 4; c++) {
          const float* kr = &Kb32[(size_t)(kb + l32) * HDIM + c * 16 + hi * 8];
          f32x4 k0 = *(const f32x4*)kr, k1 = *(const f32x4*)(kr + 4);
          s16x8 kf;
#pragma unroll
          for (int u = 0; u < 4; u++) {
            kf[u] = f2bf(k0[u]);
            kf[4 + u] = f2bf(k1[u]);
          }
          S = mfma32(kf, qf[c], S);
        }
      }
      const short* vb = &Vfb[(size_t)kt * 2048 + lane * 8];
      s16x8 va00 = *(const s16x8*)vb;
      s16x8 va10 = *(const s16x8*)(vb + 512);
      s16x8 va01 = *(const s16x8*)(vb + 1024);
      s16x8 va11 = *(const s16x8*)(vb + 1536);
      if constexpr (KFRAG) {
        if (kt + 4 <= j) {
#pragma unroll
          for (int c = 0; c < 4; c++)
            kcur[c] = *(const s16x8*)&Kfb[(size_t)(kt + 4) * 2048 + c * 512 +
                                          lane * 8];
        }
      }
      if (kt == j) {
#pragma unroll
        for (int r = 0; r < 16; r++) {
          int keyl = (r & 3) + 8 * (r >> 2) + 4 * hi;
          S[r] = (keyl <= l32) ? S[r] : -1e30f;
        }
      }
      float t8[8];
#pragma unroll
      for (int r = 0; r < 8; r++) t8[r] = fmaxf(S[2 * r], S[2 * r + 1]);
      float tmax = fmaxf(fmaxf(fmaxf(t8[0], t8[1]), fmaxf(t8[2], t8[3])),
                         fmaxf(fmaxf(t8[4], t8[5]), fmaxf(t8[6], t8[7])));
      tmax = fmaxf(tmax, __shfl_xor(tmax, 32));
      if (!__all(tmax <= m + 11.0f)) {
        float mn = fmaxf(m, tmax);
        float alpha = __builtin_amdgcn_exp2f(m - mn);
        ll *= alpha;
#pragma unroll
        for (int r = 0; r < 16; r++) {
          acc0[r] *= alpha;
          acc1[r] *= alpha;
        }
        m = mn;
      }
#pragma unroll
      for (int r = 0; r < 16; r++) S[r] = __builtin_amdgcn_exp2f(S[r] - m);
      float s8[8];
#pragma unroll
      for (int r = 0; r < 8; r++) s8[r] = S[2 * r] + S[2 * r + 1];
      float rs = ((s8[0] + s8[1]) + (s8[2] + s8[3])) +
                 ((s8[4] + s8[5]) + (s8[6] + s8[7]));
      rs += __shfl_xor(rs, 32);
      ll += rs;
      u32x4 pb0v, pb1v;
#pragma unroll
      for (int g = 0; g < 4; g++) {
        unsigned int lo = (unsigned short)f2bf(S[2 * g]);
        unsigned int h16 = (unsigned short)f2bf(S[2 * g + 1]);
        pb0v[g] = lo | (h16 << 16);
        unsigned int lo2 = (unsigned short)f2bf(S[8 + 2 * g]);
        unsigned int h162 = (unsigned short)f2bf(S[9 + 2 * g]);
        pb1v[g] = lo2 | (h162 << 16);
      }
      s16x8 pb0 = __builtin_bit_cast(s16x8, pb0v);
      s16x8 pb1 = __builtin_bit_cast(s16x8, pb1v);
      acc0 = mfma32(va00, pb0, acc0);
      acc1 = mfma32(va10, pb0, acc1);
      acc0 = mfma32(va01, pb1, acc0);
      acc1 = mfma32(va11, pb1, acc1);
    }

    // ---- combine the 4 per-wave partials (tree merge via LDS) ----
    if (w & 1) {
      float* dst = &XFER[w >> 1][lane][0];
      dst[0] = m; dst[1] = ll;
#pragma unroll
      for (int r = 0; r < 16; r++) { dst[2 + r] = acc0[r]; dst[18 + r] = acc1[r]; }
    }
    __syncthreads();
    if (!(w & 1)) {
      const float* src = &XFER[w >> 1][lane][0];
      float m2 = src[0], l2 = src[1];
      float M = fmaxf(m, m2);
      float a1 = __builtin_amdgcn_exp2f(m - M);
      float a2 = __builtin_amdgcn_exp2f(m2 - M);
      ll = ll * a1 + l2 * a2;
#pragma unroll
      for (int r = 0; r < 16; r++) {
        acc0[r] = acc0[r] * a1 + src[2 + r] * a2;
        acc1[r] = acc1[r] * a1 + src[18 + r] * a2;
      }
      m = M;
    }
    __syncthreads();
    if (w == 2) {
      float* dst = &XFER[0][lane][0];
      dst[0] = m; dst[1] = ll;
#pragma unroll
      for (int r = 0; r < 16; r++) { dst[2 + r] = acc0[r]; dst[18 + r] = acc1[r]; }
    }
    __syncthreads();
    if (w == 0) {
      const float* src = &XFER[0][lane][0];
      float m2 = src[0], l2 = src[1];
      float M = fmaxf(m, m2);
      float a1 = __builtin_amdgcn_exp2f(m - M);
      float a2 = __builtin_amdgcn_exp2f(m2 - M);
      ll = ll * a1 + l2 * a2;
#pragma unroll
      for (int r = 0; r < 16; r++) {
        acc0[r] = acc0[r] * a1 + src[2 + r] * a2;
        acc1[r] = acc1[r] * a1 + src[18 + r] * a2;
      }
      float inv = 1.f / ll;
      size_t rowbase = ((size_t)(b * S_LEN + qb + l32)) * DMODEL + h * HDIM;
#pragma unroll
      for (int g = 0; g < 4; g++) {
        s16x4 o0, o1;
#pragma unroll
        for (int u = 0; u < 4; u++) {
          o0[u] = f2bf(acc0[4 * g + u] * inv);
          o1[u] = f2bf(acc1[4 * g + u] * inv);
        }
        *(s16x4*)&AO[rowbase + 8 * g + 4 * hi] = o0;
        *(s16x4*)&AO[rowbase + 32 + 8 * g + 4 * hi] = o1;
      }
    }
    __syncthreads();
  }
}

__global__ __launch_bounds__(256, 4) void attn_fwd_frag(
    const short* __restrict__ Q, const short* __restrict__ Kf,
    const short* __restrict__ Vf, short* __restrict__ AO) {
  attn_body<true>(Q, Kf, Vf, AO);
}
__global__ __launch_bounds__(256, 4) void attn_fwd_kf32(
    const short* __restrict__ Q, const float* __restrict__ K,
    const short* __restrict__ Vf, short* __restrict__ AO) {
  attn_body<false>(Q, K, Vf, AO);
}

extern "C" void kernel_launch(void* const* d_in, const int* in_sizes, int n_in,
                              void* d_out, int out_size, void* d_ws,
                              size_t ws_size, hipStream_t stream) {
  const float* x = (const float*)d_in[0];
  const float* w_qkv = (const float*)d_in[1];
  const float* b_qkv = (const float*)d_in[2];
  const float* w_proj = (const float*)d_in[3];
  const float* b_proj = (const float*)d_in[4];
  float* out = (float*)d_out;
  float* presentK = out + OUT_ELEMS;            // f32 [bh][S][64]
  float* presentV = presentK + HEAD_ELEMS;      // f32 [bh][S][64]

  short* xbf = (short*)out;  // dead-until-proj region

  short* ws = (short*)d_ws;
  const bool kbf16 = ws_size >= (size_t)35651584;

  short *Qw, *Vf, *wprojT, *wqkvT, *attnout, *Kf;
  if (kbf16) {
    Qw = ws;
    Kf = ws + 4194304;
    Vf = ws + 8388608;
    wprojT = ws + 12582912;
    wqkvT = ws + 13631488;
    attnout = ws + 13631488;
  } else {
    if (ws_size < (size_t)27262976) return;
    Qw = ws;
    Vf = ws + 4194304;
    wprojT = ws + 8388608;
    wqkvT = ws + 9437184;
    attnout = ws + 9437184;
    Kf = nullptr;
  }

  // fused preprocessing (x cvt + both weight transposes)
  preproc<<<dim3(4096), 256, 0, stream>>>(x, xbf, w_qkv, wqkvT, w_proj,
                                          wprojT);
  // QKV projection: Q(pre-scaled)->Qw bf16, K/V->present f32
  gemm_bt<0><<<dim3(24, 32), 256, 0, stream>>>(xbf, wqkvT, b_qkv, Qw,
                                               presentK, 4096, 3072, 1024);
  // fused fragment-linear repacks
  {
    int koff = kbf16 ? 512 : 0;
    kvfrag<<<dim3(koff + 1024), 256, 0, stream>>>(presentK, presentV, Kf, Vf,
                                                  koff);
  }
  // causal attention
  if (kbf16)
    attn_fwd_frag<<<dim3(1024), 256, 0, stream>>>(Qw, Kf, Vf, attnout);
  else
    attn_fwd_kf32<<<dim3(1024), 256, 0, stream>>>(Qw, presentK, Vf, attnout);
  // output projection -> f32 out (xbf dead by now)
  gemm_bt<1><<<dim3(8, 32), 256, 0, stream>>>(attnout, wprojT, b_proj,
                                              nullptr, out, 4096, 1024, 1024);
}